// Round 24
// baseline (585.853 us; speedup 1.0000x reference)
//
#include <hip/hip_runtime.h>

// GCN 2-layer + mean pool. fp8(e4m3) dis-prescaled tables (64-B rows), f32 math.
//   h'[r] = (x@W)[r] * dis[r];  out_d = relu(dis_d * (sum_j h'[j] + h'[d]) + b)
// Build: slim pass_a (bucket by dst>>7) -> bscan -> bucket_csr (src*64)
//        -> degree counting-sort (perm) so agg waves get equal-degree nodes.
// GEMM: K-chunked staging (33.8 KB LDS), unroll 2 (VGPR ~88, no spill).
// Aggregate: octant-per-node over perm (md ~= deg, no max-of-8 padding),
// 4-deep pipeline, 2 node-groups per wave.

#define CAP 8192
#define PA_T 4096

typedef float v2f __attribute__((vector_size(8)));

__device__ __forceinline__ void acc_fp8x8(uint2 w, v2f* acc) {
    acc[0] += __builtin_amdgcn_cvt_pk_f32_fp8((int)w.x, false);
    acc[1] += __builtin_amdgcn_cvt_pk_f32_fp8((int)w.x, true);
    acc[2] += __builtin_amdgcn_cvt_pk_f32_fp8((int)w.y, false);
    acc[3] += __builtin_amdgcn_cvt_pk_f32_fp8((int)w.y, true);
}
__device__ __forceinline__ unsigned f32x4_to_fp8(float a, float b, float c, float d) {
    int w = 0;
    w = __builtin_amdgcn_cvt_pk_fp8_f32(a, b, w, false);
    w = __builtin_amdgcn_cvt_pk_fp8_f32(c, d, w, true);
    return (unsigned)w;
}

// Bucket edges by dst>>7 (slim LDS; hist reused as writeout delta).
__global__ __launch_bounds__(256)
void pass_a_kernel(const int* __restrict__ src, const int* __restrict__ dst,
                   int* __restrict__ bcur, unsigned* __restrict__ keys, int e, int nb) {
    __shared__ unsigned skeys[PA_T];        // 16 KB
    __shared__ unsigned short sbkt[PA_T];   // 8 KB
    __shared__ int hist[1024];
    __shared__ int base[1024];
    __shared__ int curs[1024];
    __shared__ int wsum[4];

    const int tid = threadIdx.x;
    const int lane = tid & 63;
    const int wv = tid >> 6;
    const int e0 = blockIdx.x * PA_T;
    const int cnt = min(PA_T, e - e0);

    for (int i = tid; i < 1024; i += 256) hist[i] = 0;
    __syncthreads();

    for (int i = tid; i < cnt; i += 256) {
        int d = dst[e0 + i];
        atomicAdd(&hist[d >> 7], 1);
    }
    __syncthreads();

    {   // exclusive scan of hist[0..1023] via wave shuffle
        int t4 = tid * 4;
        int a0 = hist[t4], a1 = hist[t4 + 1], a2 = hist[t4 + 2], a3 = hist[t4 + 3];
        int tsum = a0 + a1 + a2 + a3;
        int inc = tsum;
        for (int off = 1; off < 64; off <<= 1) {
            int v = __shfl_up(inc, off);
            if (lane >= off) inc += v;
        }
        if (lane == 63) wsum[wv] = inc;
        __syncthreads();
        int wbase = 0;
#pragma unroll
        for (int w = 0; w < 4; ++w) wbase += (w < wv) ? wsum[w] : 0;
        int ex = wbase + inc - tsum;
        base[t4] = ex;
        base[t4 + 1] = ex + a0;
        base[t4 + 2] = ex + a0 + a1;
        base[t4 + 3] = ex + a0 + a1 + a2;
        curs[t4] = ex;
        curs[t4 + 1] = ex + a0;
        curs[t4 + 2] = ex + a0 + a1;
        curs[t4 + 3] = ex + a0 + a1 + a2;
    }
    __syncthreads();

    for (int i = tid; i < cnt; i += 256) {
        int s = src[e0 + i], d = dst[e0 + i];
        int b = d >> 7;
        int pos = atomicAdd(&curs[b], 1);
        skeys[pos] = ((unsigned)s << 7) | (unsigned)(d & 127);
        sbkt[pos] = (unsigned short)b;
    }
    __syncthreads();

    for (int b = tid; b < nb; b += 256) {
        int c = hist[b];
        int gb = c ? atomicAdd(&bcur[b], c) : 0;
        hist[b] = gb - base[b];
    }
    __syncthreads();

    for (int i = tid; i < cnt; i += 256) {
        int b = sbkt[i];
        keys[(size_t)b * CAP + hist[b] + i] = skeys[i];
    }
}

__global__ __launch_bounds__(1024)
void bscan_kernel(const int* __restrict__ bcur, int* __restrict__ bbase,
                  int* __restrict__ rowptr, int nb, int n) {
    __shared__ int lds[1024];
    int t = threadIdx.x;
    int v = (t < nb) ? bcur[t] : 0;
    lds[t] = v;
    __syncthreads();
    for (int off = 1; off < 1024; off <<= 1) {
        int a = (t >= off) ? lds[t - off] : 0;
        __syncthreads();
        lds[t] += a;
        __syncthreads();
    }
    if (t < nb) bbase[t] = lds[t] - v;
    if (t == 1023) rowptr[n] = lds[1023];
}

// Per bucket: histogram -> scan -> dis + rowptr; LDS sort -> csr_src (src*64).
__global__ __launch_bounds__(256)
void bucket_csr_kernel(const unsigned* __restrict__ keys, const int* __restrict__ bcur,
                       const int* __restrict__ bbase, float* __restrict__ dis,
                       int* __restrict__ rowptr, int* __restrict__ csr_src, int n) {
    __shared__ int ssrc[CAP];   // 32 KB
    __shared__ int hist[128];
    __shared__ int curs[128];
    __shared__ int sc[256];

    const int tid = threadIdx.x;
    const int b = blockIdx.x;
    const int v0 = b << 7;
    const int nv = min(128, n - v0);
    const int ne = bcur[b];
    const int gb = bbase[b];
    const size_t kb = (size_t)b * CAP;

    if (tid < 128) hist[tid] = 0;
    __syncthreads();
    for (int i = tid; i < ne; i += 256) atomicAdd(&hist[keys[kb + i] & 127u], 1);
    __syncthreads();

    int hv = (tid < 128) ? hist[tid] : 0;
    sc[tid] = hv;
    __syncthreads();
    for (int off = 1; off < 128; off <<= 1) {
        int a = (tid >= off) ? sc[tid - off] : 0;
        __syncthreads();
        sc[tid] += a;
        __syncthreads();
    }
    if (tid < 128) {
        int ex = sc[tid] - hv;
        curs[tid] = ex;
        if (tid < nv) {
            rowptr[v0 + tid] = gb + ex;
            dis[v0 + tid] = rsqrtf((float)hv + 1.0f);
        }
    }
    __syncthreads();

    for (int i = tid; i < ne; i += 256) {
        unsigned k = keys[kb + i];
        int pos = atomicAdd(&curs[k & 127u], 1);
        ssrc[pos] = (int)((k >> 7) << 6);   // src * 64 bytes
    }
    __syncthreads();

    for (int i = tid; i < ne; i += 256) csr_src[gb + i] = ssrc[i];
}

// --- degree counting-sort: perm = nodes ordered by degree ---
__global__ __launch_bounds__(256)
void deg_hist_kernel(const int* __restrict__ rowptr, int* __restrict__ dhist, int n) {
    int i = blockIdx.x * 256 + threadIdx.x;
    int stride = gridDim.x * 256;
    for (; i < n; i += stride) {
        int d = min(rowptr[i + 1] - rowptr[i], 255);
        atomicAdd(&dhist[d], 1);
    }
}

__global__ __launch_bounds__(256)
void deg_scan_kernel(const int* __restrict__ dhist, int* __restrict__ dcur) {
    __shared__ int lds[256];
    int t = threadIdx.x;
    int v = dhist[t];
    lds[t] = v;
    __syncthreads();
    for (int off = 1; off < 256; off <<= 1) {
        int a = (t >= off) ? lds[t - off] : 0;
        __syncthreads();
        lds[t] += a;
        __syncthreads();
    }
    dcur[t] = lds[t] - v;   // exclusive
}

__global__ __launch_bounds__(256)
void deg_place_kernel(const int* __restrict__ rowptr, int* __restrict__ dcur,
                      int* __restrict__ perm, int n) {
    int i = blockIdx.x * 256 + threadIdx.x;
    int stride = gridDim.x * 256;
    for (; i < n; i += stride) {
        int d = min(rowptr[i + 1] - rowptr[i], 255);
        int pos = atomicAdd(&dcur[d], 1);
        perm[pos] = i;
    }
}

// C_row = (A @ B) * dis[row], fp8 64-B rows. K staged in 64-wide chunks
// (As[64][68] + Bs[64][64] = 33.8 KB LDS). Unroll 2 caps VGPR.
template <int K, bool FP8_IN>
__global__ __launch_bounds__(256)
void gemm_kernel(const void* __restrict__ Av, const float* __restrict__ B,
                 const float* __restrict__ dis, unsigned char* __restrict__ H, int n) {
    constexpr int KC = 64;
    constexpr int KP = KC + 4;
    __shared__ float As[64 * KP];
    __shared__ float Bs[KC * 64];
    const int tid = threadIdx.x;
    const int row0 = blockIdx.x * 64;
    const int tr = tid >> 4;
    const int tc = tid & 15;

    float acc[4][4];
#pragma unroll
    for (int j = 0; j < 4; ++j)
#pragma unroll
        for (int i = 0; i < 4; ++i) acc[j][i] = 0.f;

    for (int kc = 0; kc < K / KC; ++kc) {
        if (kc > 0) __syncthreads();
        for (int idx = tid; idx < 64 * 16; idx += 256) {
            int row = idx >> 4;
            int c4  = idx & 15;
            float4 v = make_float4(0.f, 0.f, 0.f, 0.f);
            int r = row0 + row;
            if (r < n) {
                if (FP8_IN) {
                    unsigned w = *reinterpret_cast<const unsigned*>(
                        (const unsigned char*)Av + (size_t)r * K + kc * KC + c4 * 4);
                    v2f lo = __builtin_amdgcn_cvt_pk_f32_fp8((int)w, false);
                    v2f hi = __builtin_amdgcn_cvt_pk_f32_fp8((int)w, true);
                    v = make_float4(lo[0], lo[1], hi[0], hi[1]);
                } else {
                    v = *reinterpret_cast<const float4*>(
                        (const float*)Av + (size_t)r * K + kc * KC + c4 * 4);
                }
            }
            *reinterpret_cast<float4*>(&As[row * KP + c4 * 4]) = v;
        }
        for (int idx = tid; idx < KC * 16; idx += 256) {
            int row = idx >> 4, c4 = idx & 15;
            *reinterpret_cast<float4*>(&Bs[row * 64 + c4 * 4]) =
                *reinterpret_cast<const float4*>(B + (size_t)(kc * KC + row) * 64 + c4 * 4);
        }
        __syncthreads();

#pragma unroll 2
        for (int k4 = 0; k4 < KC / 4; ++k4) {
            float4 a[4], bq[4];
#pragma unroll
            for (int j = 0; j < 4; ++j)
                a[j] = *reinterpret_cast<const float4*>(&As[(tr * 4 + j) * KP + k4 * 4]);
#pragma unroll
            for (int kk = 0; kk < 4; ++kk)
                bq[kk] = *reinterpret_cast<const float4*>(&Bs[(k4 * 4 + kk) * 64 + tc * 4]);
#pragma unroll
            for (int kk = 0; kk < 4; ++kk) {
#pragma unroll
                for (int j = 0; j < 4; ++j) {
                    float av = (kk == 0) ? a[j].x : (kk == 1) ? a[j].y : (kk == 2) ? a[j].z : a[j].w;
                    acc[j][0] = fmaf(av, bq[kk].x, acc[j][0]);
                    acc[j][1] = fmaf(av, bq[kk].y, acc[j][1]);
                    acc[j][2] = fmaf(av, bq[kk].z, acc[j][2]);
                    acc[j][3] = fmaf(av, bq[kk].w, acc[j][3]);
                }
            }
        }
    }

#pragma unroll
    for (int j = 0; j < 4; ++j) {
        int r = row0 + tr * 4 + j;
        if (r < n) {
            float ds = dis[r];
            unsigned w = f32x4_to_fp8(acc[j][0] * ds, acc[j][1] * ds,
                                      acc[j][2] * ds, acc[j][3] * ds);
            *reinterpret_cast<unsigned*>(H + (size_t)r * 64 + tc * 4) = w;
        }
    }
}

// OCTANT-PER-NODE aggregation over degree-sorted perm. Wave handles perm
// slots g*8..g*8+7; octant o owns node perm[g*8+o] (8 lanes = one 64-B row).
// 4 edges in flight per octant; md ~= deg within a sorted group.
template <bool WRITE_OUT>
__global__ __launch_bounds__(256)
void agg_kernel(const int* __restrict__ rowptr, const int* __restrict__ csr_src,
                const int* __restrict__ perm,
                const unsigned char* __restrict__ h, const float* __restrict__ dis,
                const float* __restrict__ bias,
                unsigned char* __restrict__ out, float* __restrict__ outsum,
                int n, int zoff, float inv_n) {
    const int tid = threadIdx.x;
    const int lane = tid & 63;
    const int o = lane >> 3;
    const int cl = lane & 7;
    const int wid = blockIdx.x * 4 + (tid >> 6);
    const int nw = gridDim.x * 4;
    const int ngroups = (n + 7) >> 3;

    float bl[8];
    {
        float4 b0 = *reinterpret_cast<const float4*>(bias + cl * 8);
        float4 b1 = *reinterpret_cast<const float4*>(bias + cl * 8 + 4);
        bl[0] = b0.x; bl[1] = b0.y; bl[2] = b0.z; bl[3] = b0.w;
        bl[4] = b1.x; bl[5] = b1.y; bl[6] = b1.z; bl[7] = b1.w;
    }
    float bsum[8];
#pragma unroll
    for (int k = 0; k < 8; ++k) bsum[k] = 0.f;

    for (int g = wid; g < ngroups; g += nw) {
        const int pidx = g * 8 + o;
        const bool live = pidx < n;
        const int node = live ? perm[pidx] : (n - 1);
        const int rp0 = rowptr[node];
        const int deg = live ? (rowptr[node + 1] - rp0) : 0;
        const float ds = dis[node];

        v2f acc[4];
        {
            int so = live ? node * 64 : zoff;
            uint2 hw = *reinterpret_cast<const uint2*>(h + (size_t)(unsigned)so + cl * 8);
            acc[0] = __builtin_amdgcn_cvt_pk_f32_fp8((int)hw.x, false);
            acc[1] = __builtin_amdgcn_cvt_pk_f32_fp8((int)hw.x, true);
            acc[2] = __builtin_amdgcn_cvt_pk_f32_fp8((int)hw.y, false);
            acc[3] = __builtin_amdgcn_cvt_pk_f32_fp8((int)hw.y, true);
        }

        int md = deg;
        md = max(md, __shfl_xor(md, 8));
        md = max(md, __shfl_xor(md, 16));
        md = max(md, __shfl_xor(md, 32));

        if (md > 0) {
            int o0 = (0 < deg) ? csr_src[rp0]     : zoff;
            int o1 = (1 < deg) ? csr_src[rp0 + 1] : zoff;
            int o2 = (2 < deg) ? csr_src[rp0 + 2] : zoff;
            int o3 = (3 < deg) ? csr_src[rp0 + 3] : zoff;
            for (int it = 0; it < md; it += 4) {
                uint2 g0 = *reinterpret_cast<const uint2*>(h + (size_t)(unsigned)o0 + cl * 8);
                uint2 g1 = *reinterpret_cast<const uint2*>(h + (size_t)(unsigned)o1 + cl * 8);
                uint2 g2 = *reinterpret_cast<const uint2*>(h + (size_t)(unsigned)o2 + cl * 8);
                uint2 g3 = *reinterpret_cast<const uint2*>(h + (size_t)(unsigned)o3 + cl * 8);
                int c0 = csr_src[rp0 + it + 4];
                int c1 = csr_src[rp0 + it + 5];
                int c2 = csr_src[rp0 + it + 6];
                int c3 = csr_src[rp0 + it + 7];
                o0 = (it + 4 < deg) ? c0 : zoff;
                o1 = (it + 5 < deg) ? c1 : zoff;
                o2 = (it + 6 < deg) ? c2 : zoff;
                o3 = (it + 7 < deg) ? c3 : zoff;
                acc_fp8x8(g0, acc);
                acc_fp8x8(g1, acc);
                acc_fp8x8(g2, acc);
                acc_fp8x8(g3, acc);
            }
        }

        float val[8];
#pragma unroll
        for (int k = 0; k < 4; ++k) {
            val[2 * k]     = fmaxf(fmaf(acc[k][0], ds, bl[2 * k]), 0.f);
            val[2 * k + 1] = fmaxf(fmaf(acc[k][1], ds, bl[2 * k + 1]), 0.f);
        }
        if (WRITE_OUT) {
            if (live) {
                unsigned w0 = f32x4_to_fp8(val[0], val[1], val[2], val[3]);
                unsigned w1 = f32x4_to_fp8(val[4], val[5], val[6], val[7]);
                *reinterpret_cast<uint2*>(out + (size_t)node * 64 + cl * 8) = make_uint2(w0, w1);
            }
        } else {
            if (live) {
#pragma unroll
                for (int k = 0; k < 8; ++k) bsum[k] += val[k];
            }
        }
    }

    if (!WRITE_OUT) {
        __shared__ float lds[4][64];
#pragma unroll
        for (int k = 0; k < 8; ++k) {
            float v = bsum[k];
            v += __shfl_xor(v, 8);
            v += __shfl_xor(v, 16);
            v += __shfl_xor(v, 32);
            bsum[k] = v;
        }
        const int wv = tid >> 6;
        if (o == 0) {
#pragma unroll
            for (int k = 0; k < 8; ++k) lds[wv][cl * 8 + k] = bsum[k];
        }
        __syncthreads();
        if (tid < 64) {
            float s = lds[0][tid] + lds[1][tid] + lds[2][tid] + lds[3][tid];
            atomicAdd(&outsum[tid], s * inv_n);
        }
    }
}

extern "C" void kernel_launch(void* const* d_in, const int* in_sizes, int n_in,
                              void* d_out, int out_size, void* d_ws, size_t ws_size,
                              hipStream_t stream) {
    const float* x  = (const float*)d_in[0];
    const int*   ei = (const int*)d_in[1];
    const float* W1 = (const float*)d_in[2];
    const float* b1 = (const float*)d_in[3];
    const float* W2 = (const float*)d_in[4];
    const float* b2 = (const float*)d_in[5];

    const int n = in_sizes[0] / 128;   // 100000
    const int e = in_sizes[1] / 2;     // 3200000
    const int* src = ei;
    const int* dst = ei + e;
    const int nb = (n + 127) >> 7;     // 782 (<= 1024)

    char* ws = (char*)d_ws;
    size_t off = 0;
    auto alloc = [&](size_t bytes) { void* p = ws + off; off = (off + bytes + 255) & ~(size_t)255; return p; };
    unsigned* keys = (unsigned*)alloc((size_t)nb * CAP * 4);
    int*   bcur    = (int*)  alloc((size_t)nb * 4);
    int*   bbase   = (int*)  alloc((size_t)nb * 4);
    float* dis     = (float*)alloc((size_t)n * 4);
    int*   rowptr  = (int*)  alloc((size_t)(n + 1) * 4);
    int*   csr_src = (int*)  alloc(((size_t)e + 256) * 4);   // slack for speculative loads
    int*   dhist   = (int*)  alloc(256 * 4);
    int*   dcur    = (int*)  alloc(256 * 4);
    int*   perm    = (int*)  alloc((size_t)n * 4);
    unsigned char* bufA = (unsigned char*)alloc((size_t)(n + 1) * 64);  // + zero row
    unsigned char* bufB = (unsigned char*)alloc((size_t)n * 64);

    hipMemsetAsync(bcur, 0, (size_t)nb * 4, stream);
    hipMemsetAsync(dhist, 0, 256 * 4, stream);
    hipMemsetAsync(d_out, 0, 64 * sizeof(float), stream);
    hipMemsetAsync(bufA + (size_t)n * 64, 0, 64, stream);   // zero row (both agg passes read bufA)

    const int pa_blocks = (e + PA_T - 1) / PA_T;
    pass_a_kernel<<<pa_blocks, 256, 0, stream>>>(src, dst, bcur, keys, e, nb);
    bscan_kernel<<<1, 1024, 0, stream>>>(bcur, bbase, rowptr, nb, n);
    bucket_csr_kernel<<<nb, 256, 0, stream>>>(keys, bcur, bbase, dis, rowptr, csr_src, n);
    deg_hist_kernel<<<512, 256, 0, stream>>>(rowptr, dhist, n);
    deg_scan_kernel<<<1, 256, 0, stream>>>(dhist, dcur);
    deg_place_kernel<<<512, 256, 0, stream>>>(rowptr, dcur, perm, n);

    const int gblocks = (n + 63) / 64;
    const int zoff = n * 64;
    const int agg_blocks = 1563;   // 2 node-groups per wave (measured-best)

    // Layer 1: h1' = (x@W1)*dis -> bufA (fp8)
    gemm_kernel<128, false><<<gblocks, 256, 0, stream>>>(x, W1, dis, bufA, n);
    // x2 = relu(dis * gather-sum + b1) -> bufB
    agg_kernel<true><<<agg_blocks, 256, 0, stream>>>(rowptr, csr_src, perm, bufA, dis, b1,
                                                     bufB, nullptr, n, zoff, 0.f);
    // Layer 2: h2' = (x2@W2)*dis -> bufA (zero row preserved)
    gemm_kernel<64, true><<<gblocks, 256, 0, stream>>>(bufB, W2, dis, bufA, n);
    // out = mean_n relu(dis * gather-sum + b2)
    agg_kernel<false><<<agg_blocks, 256, 0, stream>>>(rowptr, csr_src, perm, bufA, dis, b2,
                                                      nullptr, (float*)d_out, n, zoff, 1.0f / (float)n);
}

// Round 25
// 238.715 us; speedup vs baseline: 2.4542x; 2.4542x over previous
//
#include <hip/hip_runtime.h>

// GCN 2-layer + mean pool. fp8(e4m3) dis-prescaled tables (64-B rows), f32 math.
//   h'[r] = (x@W)[r] * dis[r];  out_d = relu(dis_d * (sum_j h'[j] + h'[d]) + b)
// Build: slim pass_a (bucket by dst>>7) -> bscan -> bucket_csr (src*64)
//        -> degree counting-sort via per-block LDS hist (contention-free).
// GEMM: K-chunked staging (33.8 KB LDS), unroll 2 (VGPR ~88, no spill).
// Aggregate: octant-per-node over degree-sorted perm (md ~= deg), 4-deep
// pipeline, 2 node-groups per wave.

#define CAP 8192
#define PA_T 4096
#define DS_T 4096   // nodes per deg-sort block

typedef float v2f __attribute__((vector_size(8)));

__device__ __forceinline__ void acc_fp8x8(uint2 w, v2f* acc) {
    acc[0] += __builtin_amdgcn_cvt_pk_f32_fp8((int)w.x, false);
    acc[1] += __builtin_amdgcn_cvt_pk_f32_fp8((int)w.x, true);
    acc[2] += __builtin_amdgcn_cvt_pk_f32_fp8((int)w.y, false);
    acc[3] += __builtin_amdgcn_cvt_pk_f32_fp8((int)w.y, true);
}
__device__ __forceinline__ unsigned f32x4_to_fp8(float a, float b, float c, float d) {
    int w = 0;
    w = __builtin_amdgcn_cvt_pk_fp8_f32(a, b, w, false);
    w = __builtin_amdgcn_cvt_pk_fp8_f32(c, d, w, true);
    return (unsigned)w;
}

// Bucket edges by dst>>7 (slim LDS; hist reused as writeout delta).
__global__ __launch_bounds__(256)
void pass_a_kernel(const int* __restrict__ src, const int* __restrict__ dst,
                   int* __restrict__ bcur, unsigned* __restrict__ keys, int e, int nb) {
    __shared__ unsigned skeys[PA_T];        // 16 KB
    __shared__ unsigned short sbkt[PA_T];   // 8 KB
    __shared__ int hist[1024];
    __shared__ int base[1024];
    __shared__ int curs[1024];
    __shared__ int wsum[4];

    const int tid = threadIdx.x;
    const int lane = tid & 63;
    const int wv = tid >> 6;
    const int e0 = blockIdx.x * PA_T;
    const int cnt = min(PA_T, e - e0);

    for (int i = tid; i < 1024; i += 256) hist[i] = 0;
    __syncthreads();

    for (int i = tid; i < cnt; i += 256) {
        int d = dst[e0 + i];
        atomicAdd(&hist[d >> 7], 1);
    }
    __syncthreads();

    {   // exclusive scan of hist[0..1023] via wave shuffle
        int t4 = tid * 4;
        int a0 = hist[t4], a1 = hist[t4 + 1], a2 = hist[t4 + 2], a3 = hist[t4 + 3];
        int tsum = a0 + a1 + a2 + a3;
        int inc = tsum;
        for (int off = 1; off < 64; off <<= 1) {
            int v = __shfl_up(inc, off);
            if (lane >= off) inc += v;
        }
        if (lane == 63) wsum[wv] = inc;
        __syncthreads();
        int wbase = 0;
#pragma unroll
        for (int w = 0; w < 4; ++w) wbase += (w < wv) ? wsum[w] : 0;
        int ex = wbase + inc - tsum;
        base[t4] = ex;
        base[t4 + 1] = ex + a0;
        base[t4 + 2] = ex + a0 + a1;
        base[t4 + 3] = ex + a0 + a1 + a2;
        curs[t4] = ex;
        curs[t4 + 1] = ex + a0;
        curs[t4 + 2] = ex + a0 + a1;
        curs[t4 + 3] = ex + a0 + a1 + a2;
    }
    __syncthreads();

    for (int i = tid; i < cnt; i += 256) {
        int s = src[e0 + i], d = dst[e0 + i];
        int b = d >> 7;
        int pos = atomicAdd(&curs[b], 1);
        skeys[pos] = ((unsigned)s << 7) | (unsigned)(d & 127);
        sbkt[pos] = (unsigned short)b;
    }
    __syncthreads();

    for (int b = tid; b < nb; b += 256) {
        int c = hist[b];
        int gb = c ? atomicAdd(&bcur[b], c) : 0;
        hist[b] = gb - base[b];
    }
    __syncthreads();

    for (int i = tid; i < cnt; i += 256) {
        int b = sbkt[i];
        keys[(size_t)b * CAP + hist[b] + i] = skeys[i];
    }
}

__global__ __launch_bounds__(1024)
void bscan_kernel(const int* __restrict__ bcur, int* __restrict__ bbase,
                  int* __restrict__ rowptr, int nb, int n) {
    __shared__ int lds[1024];
    int t = threadIdx.x;
    int v = (t < nb) ? bcur[t] : 0;
    lds[t] = v;
    __syncthreads();
    for (int off = 1; off < 1024; off <<= 1) {
        int a = (t >= off) ? lds[t - off] : 0;
        __syncthreads();
        lds[t] += a;
        __syncthreads();
    }
    if (t < nb) bbase[t] = lds[t] - v;
    if (t == 1023) rowptr[n] = lds[1023];
}

// Per bucket: histogram -> scan -> dis + rowptr; LDS sort -> csr_src (src*64).
__global__ __launch_bounds__(256)
void bucket_csr_kernel(const unsigned* __restrict__ keys, const int* __restrict__ bcur,
                       const int* __restrict__ bbase, float* __restrict__ dis,
                       int* __restrict__ rowptr, int* __restrict__ csr_src, int n) {
    __shared__ int ssrc[CAP];   // 32 KB
    __shared__ int hist[128];
    __shared__ int curs[128];
    __shared__ int sc[256];

    const int tid = threadIdx.x;
    const int b = blockIdx.x;
    const int v0 = b << 7;
    const int nv = min(128, n - v0);
    const int ne = bcur[b];
    const int gb = bbase[b];
    const size_t kb = (size_t)b * CAP;

    if (tid < 128) hist[tid] = 0;
    __syncthreads();
    for (int i = tid; i < ne; i += 256) atomicAdd(&hist[keys[kb + i] & 127u], 1);
    __syncthreads();

    int hv = (tid < 128) ? hist[tid] : 0;
    sc[tid] = hv;
    __syncthreads();
    for (int off = 1; off < 128; off <<= 1) {
        int a = (tid >= off) ? sc[tid - off] : 0;
        __syncthreads();
        sc[tid] += a;
        __syncthreads();
    }
    if (tid < 128) {
        int ex = sc[tid] - hv;
        curs[tid] = ex;
        if (tid < nv) {
            rowptr[v0 + tid] = gb + ex;
            dis[v0 + tid] = rsqrtf((float)hv + 1.0f);
        }
    }
    __syncthreads();

    for (int i = tid; i < ne; i += 256) {
        unsigned k = keys[kb + i];
        int pos = atomicAdd(&curs[k & 127u], 1);
        ssrc[pos] = (int)((k >> 7) << 6);   // src * 64 bytes
    }
    __syncthreads();

    for (int i = tid; i < ne; i += 256) csr_src[gb + i] = ssrc[i];
}

// --- degree counting-sort (contention-free, pass_a pattern) ---
// Phase 1: per-block LDS hist -> one global atomic per (block,bin).
__global__ __launch_bounds__(256)
void deg_hist_kernel(const int* __restrict__ rowptr, int* __restrict__ dhist, int n) {
    __shared__ int hist[256];
    const int tid = threadIdx.x;
    const int n0 = blockIdx.x * DS_T;
    const int cnt = min(DS_T, n - n0);
    hist[tid] = 0;
    __syncthreads();
    for (int i = tid; i < cnt; i += 256) {
        int d = min(rowptr[n0 + i + 1] - rowptr[n0 + i], 255);
        atomicAdd(&hist[d], 1);
    }
    __syncthreads();
    if (hist[tid]) atomicAdd(&dhist[tid], hist[tid]);
}

__global__ __launch_bounds__(256)
void deg_scan_kernel(const int* __restrict__ dhist, int* __restrict__ dbase) {
    __shared__ int lds[256];
    int t = threadIdx.x;
    int v = dhist[t];
    lds[t] = v;
    __syncthreads();
    for (int off = 1; off < 256; off <<= 1) {
        int a = (t >= off) ? lds[t - off] : 0;
        __syncthreads();
        lds[t] += a;
        __syncthreads();
    }
    dbase[t] = lds[t] - v;   // exclusive
}

// Phase 2: per-block LDS hist -> reserve per (block,bin) -> LDS-cursor place.
__global__ __launch_bounds__(256)
void deg_place_kernel(const int* __restrict__ rowptr, int* __restrict__ dcur,
                      int* __restrict__ perm, int n) {
    __shared__ int hist[256];
    __shared__ int gbase[256];
    const int tid = threadIdx.x;
    const int n0 = blockIdx.x * DS_T;
    const int cnt = min(DS_T, n - n0);
    hist[tid] = 0;
    __syncthreads();
    for (int i = tid; i < cnt; i += 256) {
        int d = min(rowptr[n0 + i + 1] - rowptr[n0 + i], 255);
        atomicAdd(&hist[d], 1);
    }
    __syncthreads();
    int c = hist[tid];
    gbase[tid] = c ? atomicAdd(&dcur[tid], c) : 0;
    hist[tid] = 0;   // reuse as local cursor
    __syncthreads();
    for (int i = tid; i < cnt; i += 256) {
        int d = min(rowptr[n0 + i + 1] - rowptr[n0 + i], 255);
        int lpos = atomicAdd(&hist[d], 1);
        perm[gbase[d] + lpos] = n0 + i;
    }
}

// C_row = (A @ B) * dis[row], fp8 64-B rows. K staged in 64-wide chunks.
template <int K, bool FP8_IN>
__global__ __launch_bounds__(256)
void gemm_kernel(const void* __restrict__ Av, const float* __restrict__ B,
                 const float* __restrict__ dis, unsigned char* __restrict__ H, int n) {
    constexpr int KC = 64;
    constexpr int KP = KC + 4;
    __shared__ float As[64 * KP];
    __shared__ float Bs[KC * 64];
    const int tid = threadIdx.x;
    const int row0 = blockIdx.x * 64;
    const int tr = tid >> 4;
    const int tc = tid & 15;

    float acc[4][4];
#pragma unroll
    for (int j = 0; j < 4; ++j)
#pragma unroll
        for (int i = 0; i < 4; ++i) acc[j][i] = 0.f;

    for (int kc = 0; kc < K / KC; ++kc) {
        if (kc > 0) __syncthreads();
        for (int idx = tid; idx < 64 * 16; idx += 256) {
            int row = idx >> 4;
            int c4  = idx & 15;
            float4 v = make_float4(0.f, 0.f, 0.f, 0.f);
            int r = row0 + row;
            if (r < n) {
                if (FP8_IN) {
                    unsigned w = *reinterpret_cast<const unsigned*>(
                        (const unsigned char*)Av + (size_t)r * K + kc * KC + c4 * 4);
                    v2f lo = __builtin_amdgcn_cvt_pk_f32_fp8((int)w, false);
                    v2f hi = __builtin_amdgcn_cvt_pk_f32_fp8((int)w, true);
                    v = make_float4(lo[0], lo[1], hi[0], hi[1]);
                } else {
                    v = *reinterpret_cast<const float4*>(
                        (const float*)Av + (size_t)r * K + kc * KC + c4 * 4);
                }
            }
            *reinterpret_cast<float4*>(&As[row * KP + c4 * 4]) = v;
        }
        for (int idx = tid; idx < KC * 16; idx += 256) {
            int row = idx >> 4, c4 = idx & 15;
            *reinterpret_cast<float4*>(&Bs[row * 64 + c4 * 4]) =
                *reinterpret_cast<const float4*>(B + (size_t)(kc * KC + row) * 64 + c4 * 4);
        }
        __syncthreads();

#pragma unroll 2
        for (int k4 = 0; k4 < KC / 4; ++k4) {
            float4 a[4], bq[4];
#pragma unroll
            for (int j = 0; j < 4; ++j)
                a[j] = *reinterpret_cast<const float4*>(&As[(tr * 4 + j) * KP + k4 * 4]);
#pragma unroll
            for (int kk = 0; kk < 4; ++kk)
                bq[kk] = *reinterpret_cast<const float4*>(&Bs[(k4 * 4 + kk) * 64 + tc * 4]);
#pragma unroll
            for (int kk = 0; kk < 4; ++kk) {
#pragma unroll
                for (int j = 0; j < 4; ++j) {
                    float av = (kk == 0) ? a[j].x : (kk == 1) ? a[j].y : (kk == 2) ? a[j].z : a[j].w;
                    acc[j][0] = fmaf(av, bq[kk].x, acc[j][0]);
                    acc[j][1] = fmaf(av, bq[kk].y, acc[j][1]);
                    acc[j][2] = fmaf(av, bq[kk].z, acc[j][2]);
                    acc[j][3] = fmaf(av, bq[kk].w, acc[j][3]);
                }
            }
        }
    }

#pragma unroll
    for (int j = 0; j < 4; ++j) {
        int r = row0 + tr * 4 + j;
        if (r < n) {
            float ds = dis[r];
            unsigned w = f32x4_to_fp8(acc[j][0] * ds, acc[j][1] * ds,
                                      acc[j][2] * ds, acc[j][3] * ds);
            *reinterpret_cast<unsigned*>(H + (size_t)r * 64 + tc * 4) = w;
        }
    }
}

// OCTANT-PER-NODE aggregation over degree-sorted perm (md ~= deg).
template <bool WRITE_OUT>
__global__ __launch_bounds__(256)
void agg_kernel(const int* __restrict__ rowptr, const int* __restrict__ csr_src,
                const int* __restrict__ perm,
                const unsigned char* __restrict__ h, const float* __restrict__ dis,
                const float* __restrict__ bias,
                unsigned char* __restrict__ out, float* __restrict__ outsum,
                int n, int zoff, float inv_n) {
    const int tid = threadIdx.x;
    const int lane = tid & 63;
    const int o = lane >> 3;
    const int cl = lane & 7;
    const int wid = blockIdx.x * 4 + (tid >> 6);
    const int nw = gridDim.x * 4;
    const int ngroups = (n + 7) >> 3;

    float bl[8];
    {
        float4 b0 = *reinterpret_cast<const float4*>(bias + cl * 8);
        float4 b1 = *reinterpret_cast<const float4*>(bias + cl * 8 + 4);
        bl[0] = b0.x; bl[1] = b0.y; bl[2] = b0.z; bl[3] = b0.w;
        bl[4] = b1.x; bl[5] = b1.y; bl[6] = b1.z; bl[7] = b1.w;
    }
    float bsum[8];
#pragma unroll
    for (int k = 0; k < 8; ++k) bsum[k] = 0.f;

    for (int g = wid; g < ngroups; g += nw) {
        const int pidx = g * 8 + o;
        const bool live = pidx < n;
        const int node = live ? perm[pidx] : (n - 1);
        const int rp0 = rowptr[node];
        const int deg = live ? (rowptr[node + 1] - rp0) : 0;
        const float ds = dis[node];

        v2f acc[4];
        {
            int so = live ? node * 64 : zoff;
            uint2 hw = *reinterpret_cast<const uint2*>(h + (size_t)(unsigned)so + cl * 8);
            acc[0] = __builtin_amdgcn_cvt_pk_f32_fp8((int)hw.x, false);
            acc[1] = __builtin_amdgcn_cvt_pk_f32_fp8((int)hw.x, true);
            acc[2] = __builtin_amdgcn_cvt_pk_f32_fp8((int)hw.y, false);
            acc[3] = __builtin_amdgcn_cvt_pk_f32_fp8((int)hw.y, true);
        }

        int md = deg;
        md = max(md, __shfl_xor(md, 8));
        md = max(md, __shfl_xor(md, 16));
        md = max(md, __shfl_xor(md, 32));

        if (md > 0) {
            int o0 = (0 < deg) ? csr_src[rp0]     : zoff;
            int o1 = (1 < deg) ? csr_src[rp0 + 1] : zoff;
            int o2 = (2 < deg) ? csr_src[rp0 + 2] : zoff;
            int o3 = (3 < deg) ? csr_src[rp0 + 3] : zoff;
            for (int it = 0; it < md; it += 4) {
                uint2 g0 = *reinterpret_cast<const uint2*>(h + (size_t)(unsigned)o0 + cl * 8);
                uint2 g1 = *reinterpret_cast<const uint2*>(h + (size_t)(unsigned)o1 + cl * 8);
                uint2 g2 = *reinterpret_cast<const uint2*>(h + (size_t)(unsigned)o2 + cl * 8);
                uint2 g3 = *reinterpret_cast<const uint2*>(h + (size_t)(unsigned)o3 + cl * 8);
                int c0 = csr_src[rp0 + it + 4];
                int c1 = csr_src[rp0 + it + 5];
                int c2 = csr_src[rp0 + it + 6];
                int c3 = csr_src[rp0 + it + 7];
                o0 = (it + 4 < deg) ? c0 : zoff;
                o1 = (it + 5 < deg) ? c1 : zoff;
                o2 = (it + 6 < deg) ? c2 : zoff;
                o3 = (it + 7 < deg) ? c3 : zoff;
                acc_fp8x8(g0, acc);
                acc_fp8x8(g1, acc);
                acc_fp8x8(g2, acc);
                acc_fp8x8(g3, acc);
            }
        }

        float val[8];
#pragma unroll
        for (int k = 0; k < 4; ++k) {
            val[2 * k]     = fmaxf(fmaf(acc[k][0], ds, bl[2 * k]), 0.f);
            val[2 * k + 1] = fmaxf(fmaf(acc[k][1], ds, bl[2 * k + 1]), 0.f);
        }
        if (WRITE_OUT) {
            if (live) {
                unsigned w0 = f32x4_to_fp8(val[0], val[1], val[2], val[3]);
                unsigned w1 = f32x4_to_fp8(val[4], val[5], val[6], val[7]);
                *reinterpret_cast<uint2*>(out + (size_t)node * 64 + cl * 8) = make_uint2(w0, w1);
            }
        } else {
            if (live) {
#pragma unroll
                for (int k = 0; k < 8; ++k) bsum[k] += val[k];
            }
        }
    }

    if (!WRITE_OUT) {
        __shared__ float lds[4][64];
#pragma unroll
        for (int k = 0; k < 8; ++k) {
            float v = bsum[k];
            v += __shfl_xor(v, 8);
            v += __shfl_xor(v, 16);
            v += __shfl_xor(v, 32);
            bsum[k] = v;
        }
        const int wv = tid >> 6;
        if (o == 0) {
#pragma unroll
            for (int k = 0; k < 8; ++k) lds[wv][cl * 8 + k] = bsum[k];
        }
        __syncthreads();
        if (tid < 64) {
            float s = lds[0][tid] + lds[1][tid] + lds[2][tid] + lds[3][tid];
            atomicAdd(&outsum[tid], s * inv_n);
        }
    }
}

extern "C" void kernel_launch(void* const* d_in, const int* in_sizes, int n_in,
                              void* d_out, int out_size, void* d_ws, size_t ws_size,
                              hipStream_t stream) {
    const float* x  = (const float*)d_in[0];
    const int*   ei = (const int*)d_in[1];
    const float* W1 = (const float*)d_in[2];
    const float* b1 = (const float*)d_in[3];
    const float* W2 = (const float*)d_in[4];
    const float* b2 = (const float*)d_in[5];

    const int n = in_sizes[0] / 128;   // 100000
    const int e = in_sizes[1] / 2;     // 3200000
    const int* src = ei;
    const int* dst = ei + e;
    const int nb = (n + 127) >> 7;     // 782 (<= 1024)

    char* ws = (char*)d_ws;
    size_t off = 0;
    auto alloc = [&](size_t bytes) { void* p = ws + off; off = (off + bytes + 255) & ~(size_t)255; return p; };
    unsigned* keys = (unsigned*)alloc((size_t)nb * CAP * 4);
    int*   bcur    = (int*)  alloc((size_t)nb * 4);
    int*   bbase   = (int*)  alloc((size_t)nb * 4);
    float* dis     = (float*)alloc((size_t)n * 4);
    int*   rowptr  = (int*)  alloc((size_t)(n + 1) * 4);
    int*   csr_src = (int*)  alloc(((size_t)e + 256) * 4);   // slack for speculative loads
    int*   dhist   = (int*)  alloc(256 * 4);
    int*   dcur    = (int*)  alloc(256 * 4);
    int*   perm    = (int*)  alloc((size_t)n * 4);
    unsigned char* bufA = (unsigned char*)alloc((size_t)(n + 1) * 64);  // + zero row
    unsigned char* bufB = (unsigned char*)alloc((size_t)n * 64);

    hipMemsetAsync(bcur, 0, (size_t)nb * 4, stream);
    hipMemsetAsync(dhist, 0, 256 * 4, stream);
    hipMemsetAsync(d_out, 0, 64 * sizeof(float), stream);
    hipMemsetAsync(bufA + (size_t)n * 64, 0, 64, stream);   // zero row (both agg passes read bufA)

    const int pa_blocks = (e + PA_T - 1) / PA_T;
    const int ds_blocks = (n + DS_T - 1) / DS_T;
    pass_a_kernel<<<pa_blocks, 256, 0, stream>>>(src, dst, bcur, keys, e, nb);
    bscan_kernel<<<1, 1024, 0, stream>>>(bcur, bbase, rowptr, nb, n);
    bucket_csr_kernel<<<nb, 256, 0, stream>>>(keys, bcur, bbase, dis, rowptr, csr_src, n);
    deg_hist_kernel<<<ds_blocks, 256, 0, stream>>>(rowptr, dhist, n);
    deg_scan_kernel<<<1, 256, 0, stream>>>(dhist, dcur);
    deg_place_kernel<<<ds_blocks, 256, 0, stream>>>(rowptr, dcur, perm, n);

    const int gblocks = (n + 63) / 64;
    const int zoff = n * 64;
    const int agg_blocks = 1563;   // 2 node-groups per wave (measured-best)

    // Layer 1: h1' = (x@W1)*dis -> bufA (fp8)
    gemm_kernel<128, false><<<gblocks, 256, 0, stream>>>(x, W1, dis, bufA, n);
    // x2 = relu(dis * gather-sum + b1) -> bufB
    agg_kernel<true><<<agg_blocks, 256, 0, stream>>>(rowptr, csr_src, perm, bufA, dis, b1,
                                                     bufB, nullptr, n, zoff, 0.f);
    // Layer 2: h2' = (x2@W2)*dis -> bufA (zero row preserved)
    gemm_kernel<64, true><<<gblocks, 256, 0, stream>>>(bufB, W2, dis, bufA, n);
    // out = mean_n relu(dis * gather-sum + b2)
    agg_kernel<false><<<agg_blocks, 256, 0, stream>>>(rowptr, csr_src, perm, bufA, dis, b2,
                                                      nullptr, (float*)d_out, n, zoff, 1.0f / (float)n);
}

// Round 26
// 218.142 us; speedup vs baseline: 2.6857x; 1.0943x over previous
//
#include <hip/hip_runtime.h>

// GCN 2-layer + mean pool. fp8(e4m3) dis-prescaled tables (64-B rows), f32 math.
//   h'[r] = (x@W)[r] * dis[r];  out_d = relu(dis_d * (sum_j h'[j] + h'[d]) + b)
// Build: slim pass_a (bucket by dst>>7) -> bscan -> bucket_csr (src*64).
// GEMM: K-chunked staging (33.8 KB LDS), unroll 2 (VGPR ~88, no spill).
// Aggregate: octant-per-node, 4-deep pipeline, 2 node-groups per wave
// (measured-best configuration: 65 us/layer, total ~218 us, reproduced 2x).

#define CAP 8192
#define PA_T 4096

typedef float v2f __attribute__((vector_size(8)));

__device__ __forceinline__ void acc_fp8x8(uint2 w, v2f* acc) {
    acc[0] += __builtin_amdgcn_cvt_pk_f32_fp8((int)w.x, false);
    acc[1] += __builtin_amdgcn_cvt_pk_f32_fp8((int)w.x, true);
    acc[2] += __builtin_amdgcn_cvt_pk_f32_fp8((int)w.y, false);
    acc[3] += __builtin_amdgcn_cvt_pk_f32_fp8((int)w.y, true);
}
__device__ __forceinline__ unsigned f32x4_to_fp8(float a, float b, float c, float d) {
    int w = 0;
    w = __builtin_amdgcn_cvt_pk_fp8_f32(a, b, w, false);
    w = __builtin_amdgcn_cvt_pk_fp8_f32(c, d, w, true);
    return (unsigned)w;
}

// Bucket edges by dst>>7 (slim LDS; hist reused as writeout delta).
__global__ __launch_bounds__(256)
void pass_a_kernel(const int* __restrict__ src, const int* __restrict__ dst,
                   int* __restrict__ bcur, unsigned* __restrict__ keys, int e, int nb) {
    __shared__ unsigned skeys[PA_T];        // 16 KB
    __shared__ unsigned short sbkt[PA_T];   // 8 KB
    __shared__ int hist[1024];
    __shared__ int base[1024];
    __shared__ int curs[1024];
    __shared__ int wsum[4];

    const int tid = threadIdx.x;
    const int lane = tid & 63;
    const int wv = tid >> 6;
    const int e0 = blockIdx.x * PA_T;
    const int cnt = min(PA_T, e - e0);

    for (int i = tid; i < 1024; i += 256) hist[i] = 0;
    __syncthreads();

    for (int i = tid; i < cnt; i += 256) {
        int d = dst[e0 + i];
        atomicAdd(&hist[d >> 7], 1);
    }
    __syncthreads();

    {   // exclusive scan of hist[0..1023] via wave shuffle
        int t4 = tid * 4;
        int a0 = hist[t4], a1 = hist[t4 + 1], a2 = hist[t4 + 2], a3 = hist[t4 + 3];
        int tsum = a0 + a1 + a2 + a3;
        int inc = tsum;
        for (int off = 1; off < 64; off <<= 1) {
            int v = __shfl_up(inc, off);
            if (lane >= off) inc += v;
        }
        if (lane == 63) wsum[wv] = inc;
        __syncthreads();
        int wbase = 0;
#pragma unroll
        for (int w = 0; w < 4; ++w) wbase += (w < wv) ? wsum[w] : 0;
        int ex = wbase + inc - tsum;
        base[t4] = ex;
        base[t4 + 1] = ex + a0;
        base[t4 + 2] = ex + a0 + a1;
        base[t4 + 3] = ex + a0 + a1 + a2;
        curs[t4] = ex;
        curs[t4 + 1] = ex + a0;
        curs[t4 + 2] = ex + a0 + a1;
        curs[t4 + 3] = ex + a0 + a1 + a2;
    }
    __syncthreads();

    for (int i = tid; i < cnt; i += 256) {
        int s = src[e0 + i], d = dst[e0 + i];
        int b = d >> 7;
        int pos = atomicAdd(&curs[b], 1);
        skeys[pos] = ((unsigned)s << 7) | (unsigned)(d & 127);
        sbkt[pos] = (unsigned short)b;
    }
    __syncthreads();

    for (int b = tid; b < nb; b += 256) {
        int c = hist[b];
        int gb = c ? atomicAdd(&bcur[b], c) : 0;
        hist[b] = gb - base[b];
    }
    __syncthreads();

    for (int i = tid; i < cnt; i += 256) {
        int b = sbkt[i];
        keys[(size_t)b * CAP + hist[b] + i] = skeys[i];
    }
}

__global__ __launch_bounds__(1024)
void bscan_kernel(const int* __restrict__ bcur, int* __restrict__ bbase,
                  int* __restrict__ rowptr, int nb, int n) {
    __shared__ int lds[1024];
    int t = threadIdx.x;
    int v = (t < nb) ? bcur[t] : 0;
    lds[t] = v;
    __syncthreads();
    for (int off = 1; off < 1024; off <<= 1) {
        int a = (t >= off) ? lds[t - off] : 0;
        __syncthreads();
        lds[t] += a;
        __syncthreads();
    }
    if (t < nb) bbase[t] = lds[t] - v;
    if (t == 1023) rowptr[n] = lds[1023];
}

// Per bucket: histogram -> scan -> dis + rowptr; LDS sort -> csr_src (src*64).
__global__ __launch_bounds__(256)
void bucket_csr_kernel(const unsigned* __restrict__ keys, const int* __restrict__ bcur,
                       const int* __restrict__ bbase, float* __restrict__ dis,
                       int* __restrict__ rowptr, int* __restrict__ csr_src, int n) {
    __shared__ int ssrc[CAP];   // 32 KB
    __shared__ int hist[128];
    __shared__ int curs[128];
    __shared__ int sc[256];

    const int tid = threadIdx.x;
    const int b = blockIdx.x;
    const int v0 = b << 7;
    const int nv = min(128, n - v0);
    const int ne = bcur[b];
    const int gb = bbase[b];
    const size_t kb = (size_t)b * CAP;

    if (tid < 128) hist[tid] = 0;
    __syncthreads();
    for (int i = tid; i < ne; i += 256) atomicAdd(&hist[keys[kb + i] & 127u], 1);
    __syncthreads();

    int hv = (tid < 128) ? hist[tid] : 0;
    sc[tid] = hv;
    __syncthreads();
    for (int off = 1; off < 128; off <<= 1) {
        int a = (tid >= off) ? sc[tid - off] : 0;
        __syncthreads();
        sc[tid] += a;
        __syncthreads();
    }
    if (tid < 128) {
        int ex = sc[tid] - hv;
        curs[tid] = ex;
        if (tid < nv) {
            rowptr[v0 + tid] = gb + ex;
            dis[v0 + tid] = rsqrtf((float)hv + 1.0f);
        }
    }
    __syncthreads();

    for (int i = tid; i < ne; i += 256) {
        unsigned k = keys[kb + i];
        int pos = atomicAdd(&curs[k & 127u], 1);
        ssrc[pos] = (int)((k >> 7) << 6);   // src * 64 bytes
    }
    __syncthreads();

    for (int i = tid; i < ne; i += 256) csr_src[gb + i] = ssrc[i];
}

// C_row = (A @ B) * dis[row], fp8 64-B rows. K staged in 64-wide chunks
// (As[64][68] + Bs[64][64] = 33.8 KB LDS). Unroll 2 caps VGPR.
template <int K, bool FP8_IN>
__global__ __launch_bounds__(256)
void gemm_kernel(const void* __restrict__ Av, const float* __restrict__ B,
                 const float* __restrict__ dis, unsigned char* __restrict__ H, int n) {
    constexpr int KC = 64;
    constexpr int KP = KC + 4;
    __shared__ float As[64 * KP];
    __shared__ float Bs[KC * 64];
    const int tid = threadIdx.x;
    const int row0 = blockIdx.x * 64;
    const int tr = tid >> 4;
    const int tc = tid & 15;

    float acc[4][4];
#pragma unroll
    for (int j = 0; j < 4; ++j)
#pragma unroll
        for (int i = 0; i < 4; ++i) acc[j][i] = 0.f;

    for (int kc = 0; kc < K / KC; ++kc) {
        if (kc > 0) __syncthreads();
        for (int idx = tid; idx < 64 * 16; idx += 256) {
            int row = idx >> 4;
            int c4  = idx & 15;
            float4 v = make_float4(0.f, 0.f, 0.f, 0.f);
            int r = row0 + row;
            if (r < n) {
                if (FP8_IN) {
                    unsigned w = *reinterpret_cast<const unsigned*>(
                        (const unsigned char*)Av + (size_t)r * K + kc * KC + c4 * 4);
                    v2f lo = __builtin_amdgcn_cvt_pk_f32_fp8((int)w, false);
                    v2f hi = __builtin_amdgcn_cvt_pk_f32_fp8((int)w, true);
                    v = make_float4(lo[0], lo[1], hi[0], hi[1]);
                } else {
                    v = *reinterpret_cast<const float4*>(
                        (const float*)Av + (size_t)r * K + kc * KC + c4 * 4);
                }
            }
            *reinterpret_cast<float4*>(&As[row * KP + c4 * 4]) = v;
        }
        for (int idx = tid; idx < KC * 16; idx += 256) {
            int row = idx >> 4, c4 = idx & 15;
            *reinterpret_cast<float4*>(&Bs[row * 64 + c4 * 4]) =
                *reinterpret_cast<const float4*>(B + (size_t)(kc * KC + row) * 64 + c4 * 4);
        }
        __syncthreads();

#pragma unroll 2
        for (int k4 = 0; k4 < KC / 4; ++k4) {
            float4 a[4], bq[4];
#pragma unroll
            for (int j = 0; j < 4; ++j)
                a[j] = *reinterpret_cast<const float4*>(&As[(tr * 4 + j) * KP + k4 * 4]);
#pragma unroll
            for (int kk = 0; kk < 4; ++kk)
                bq[kk] = *reinterpret_cast<const float4*>(&Bs[(k4 * 4 + kk) * 64 + tc * 4]);
#pragma unroll
            for (int kk = 0; kk < 4; ++kk) {
#pragma unroll
                for (int j = 0; j < 4; ++j) {
                    float av = (kk == 0) ? a[j].x : (kk == 1) ? a[j].y : (kk == 2) ? a[j].z : a[j].w;
                    acc[j][0] = fmaf(av, bq[kk].x, acc[j][0]);
                    acc[j][1] = fmaf(av, bq[kk].y, acc[j][1]);
                    acc[j][2] = fmaf(av, bq[kk].z, acc[j][2]);
                    acc[j][3] = fmaf(av, bq[kk].w, acc[j][3]);
                }
            }
        }
    }

#pragma unroll
    for (int j = 0; j < 4; ++j) {
        int r = row0 + tr * 4 + j;
        if (r < n) {
            float ds = dis[r];
            unsigned w = f32x4_to_fp8(acc[j][0] * ds, acc[j][1] * ds,
                                      acc[j][2] * ds, acc[j][3] * ds);
            *reinterpret_cast<unsigned*>(H + (size_t)r * 64 + tc * 4) = w;
        }
    }
}

// OCTANT-PER-NODE aggregation (measured-best). Wave handles nodes
// g*8..g*8+7; octant o (8 lanes x 8 B = one 64-B fp8 row) owns node g*8+o.
// 4 edges in flight per octant; packed-f32 accumulate; coalesced stores.
template <bool WRITE_OUT>
__global__ __launch_bounds__(256)
void agg_kernel(const int* __restrict__ rowptr, const int* __restrict__ csr_src,
                const unsigned char* __restrict__ h, const float* __restrict__ dis,
                const float* __restrict__ bias,
                unsigned char* __restrict__ out, float* __restrict__ outsum,
                int n, int zoff, float inv_n) {
    const int tid = threadIdx.x;
    const int lane = tid & 63;
    const int o = lane >> 3;
    const int cl = lane & 7;
    const int wid = blockIdx.x * 4 + (tid >> 6);
    const int nw = gridDim.x * 4;
    const int ngroups = (n + 7) >> 3;

    float bl[8];
    {
        float4 b0 = *reinterpret_cast<const float4*>(bias + cl * 8);
        float4 b1 = *reinterpret_cast<const float4*>(bias + cl * 8 + 4);
        bl[0] = b0.x; bl[1] = b0.y; bl[2] = b0.z; bl[3] = b0.w;
        bl[4] = b1.x; bl[5] = b1.y; bl[6] = b1.z; bl[7] = b1.w;
    }
    float bsum[8];
#pragma unroll
    for (int k = 0; k < 8; ++k) bsum[k] = 0.f;

    for (int g = wid; g < ngroups; g += nw) {
        const int node = g * 8 + o;
        const bool live = node < n;
        const int nc = live ? node : n - 1;
        const int rp0 = rowptr[nc];
        const int rp1 = rowptr[nc + 1];
        const int deg = live ? (rp1 - rp0) : 0;
        const float ds = dis[nc];

        v2f acc[4];
        {
            int so = live ? node * 64 : zoff;
            uint2 hw = *reinterpret_cast<const uint2*>(h + (size_t)(unsigned)so + cl * 8);
            acc[0] = __builtin_amdgcn_cvt_pk_f32_fp8((int)hw.x, false);
            acc[1] = __builtin_amdgcn_cvt_pk_f32_fp8((int)hw.x, true);
            acc[2] = __builtin_amdgcn_cvt_pk_f32_fp8((int)hw.y, false);
            acc[3] = __builtin_amdgcn_cvt_pk_f32_fp8((int)hw.y, true);
        }

        int md = deg;
        md = max(md, __shfl_xor(md, 8));
        md = max(md, __shfl_xor(md, 16));
        md = max(md, __shfl_xor(md, 32));

        if (md > 0) {
            int o0 = (0 < deg) ? csr_src[rp0]     : zoff;
            int o1 = (1 < deg) ? csr_src[rp0 + 1] : zoff;
            int o2 = (2 < deg) ? csr_src[rp0 + 2] : zoff;
            int o3 = (3 < deg) ? csr_src[rp0 + 3] : zoff;
            for (int it = 0; it < md; it += 4) {
                uint2 g0 = *reinterpret_cast<const uint2*>(h + (size_t)(unsigned)o0 + cl * 8);
                uint2 g1 = *reinterpret_cast<const uint2*>(h + (size_t)(unsigned)o1 + cl * 8);
                uint2 g2 = *reinterpret_cast<const uint2*>(h + (size_t)(unsigned)o2 + cl * 8);
                uint2 g3 = *reinterpret_cast<const uint2*>(h + (size_t)(unsigned)o3 + cl * 8);
                int c0 = csr_src[rp0 + it + 4];
                int c1 = csr_src[rp0 + it + 5];
                int c2 = csr_src[rp0 + it + 6];
                int c3 = csr_src[rp0 + it + 7];
                o0 = (it + 4 < deg) ? c0 : zoff;
                o1 = (it + 5 < deg) ? c1 : zoff;
                o2 = (it + 6 < deg) ? c2 : zoff;
                o3 = (it + 7 < deg) ? c3 : zoff;
                acc_fp8x8(g0, acc);
                acc_fp8x8(g1, acc);
                acc_fp8x8(g2, acc);
                acc_fp8x8(g3, acc);
            }
        }

        float val[8];
#pragma unroll
        for (int k = 0; k < 4; ++k) {
            val[2 * k]     = fmaxf(fmaf(acc[k][0], ds, bl[2 * k]), 0.f);
            val[2 * k + 1] = fmaxf(fmaf(acc[k][1], ds, bl[2 * k + 1]), 0.f);
        }
        if (WRITE_OUT) {
            if (live) {
                unsigned w0 = f32x4_to_fp8(val[0], val[1], val[2], val[3]);
                unsigned w1 = f32x4_to_fp8(val[4], val[5], val[6], val[7]);
                *reinterpret_cast<uint2*>(out + (size_t)node * 64 + cl * 8) = make_uint2(w0, w1);
            }
        } else {
            if (live) {
#pragma unroll
                for (int k = 0; k < 8; ++k) bsum[k] += val[k];
            }
        }
    }

    if (!WRITE_OUT) {
        __shared__ float lds[4][64];
#pragma unroll
        for (int k = 0; k < 8; ++k) {
            float v = bsum[k];
            v += __shfl_xor(v, 8);
            v += __shfl_xor(v, 16);
            v += __shfl_xor(v, 32);
            bsum[k] = v;
        }
        const int wv = tid >> 6;
        if (o == 0) {
#pragma unroll
            for (int k = 0; k < 8; ++k) lds[wv][cl * 8 + k] = bsum[k];
        }
        __syncthreads();
        if (tid < 64) {
            float s = lds[0][tid] + lds[1][tid] + lds[2][tid] + lds[3][tid];
            atomicAdd(&outsum[tid], s * inv_n);
        }
    }
}

extern "C" void kernel_launch(void* const* d_in, const int* in_sizes, int n_in,
                              void* d_out, int out_size, void* d_ws, size_t ws_size,
                              hipStream_t stream) {
    const float* x  = (const float*)d_in[0];
    const int*   ei = (const int*)d_in[1];
    const float* W1 = (const float*)d_in[2];
    const float* b1 = (const float*)d_in[3];
    const float* W2 = (const float*)d_in[4];
    const float* b2 = (const float*)d_in[5];

    const int n = in_sizes[0] / 128;   // 100000
    const int e = in_sizes[1] / 2;     // 3200000
    const int* src = ei;
    const int* dst = ei + e;
    const int nb = (n + 127) >> 7;     // 782 (<= 1024)

    char* ws = (char*)d_ws;
    size_t off = 0;
    auto alloc = [&](size_t bytes) { void* p = ws + off; off = (off + bytes + 255) & ~(size_t)255; return p; };
    unsigned* keys = (unsigned*)alloc((size_t)nb * CAP * 4);
    int*   bcur    = (int*)  alloc((size_t)nb * 4);
    int*   bbase   = (int*)  alloc((size_t)nb * 4);
    float* dis     = (float*)alloc((size_t)n * 4);
    int*   rowptr  = (int*)  alloc((size_t)(n + 1) * 4);
    int*   csr_src = (int*)  alloc(((size_t)e + 256) * 4);   // slack for speculative loads
    unsigned char* bufA = (unsigned char*)alloc((size_t)(n + 1) * 64);  // + zero row
    unsigned char* bufB = (unsigned char*)alloc((size_t)n * 64);

    hipMemsetAsync(bcur, 0, (size_t)nb * 4, stream);
    hipMemsetAsync(d_out, 0, 64 * sizeof(float), stream);
    hipMemsetAsync(bufA + (size_t)n * 64, 0, 64, stream);   // zero row (both agg passes read bufA)

    const int pa_blocks = (e + PA_T - 1) / PA_T;
    pass_a_kernel<<<pa_blocks, 256, 0, stream>>>(src, dst, bcur, keys, e, nb);
    bscan_kernel<<<1, 1024, 0, stream>>>(bcur, bbase, rowptr, nb, n);
    bucket_csr_kernel<<<nb, 256, 0, stream>>>(keys, bcur, bbase, dis, rowptr, csr_src, n);

    const int gblocks = (n + 63) / 64;
    const int zoff = n * 64;
    const int agg_blocks = 1563;   // 2 node-groups per wave (measured-best)

    // Layer 1: h1' = (x@W1)*dis -> bufA (fp8)
    gemm_kernel<128, false><<<gblocks, 256, 0, stream>>>(x, W1, dis, bufA, n);
    // x2 = relu(dis * gather-sum + b1) -> bufB
    agg_kernel<true><<<agg_blocks, 256, 0, stream>>>(rowptr, csr_src, bufA, dis, b1,
                                                     bufB, nullptr, n, zoff, 0.f);
    // Layer 2: h2' = (x2@W2)*dis -> bufA (zero row preserved)
    gemm_kernel<64, true><<<gblocks, 256, 0, stream>>>(bufB, W2, dis, bufA, n);
    // out = mean_n relu(dis * gather-sum + b2)
    agg_kernel<false><<<agg_blocks, 256, 0, stream>>>(rowptr, csr_src, bufA, dis, b2,
                                                      nullptr, (float*)d_out, n, zoff, 1.0f / (float)n);
}